// Round 5
// baseline (2844.204 us; speedup 1.0000x reference)
//
#include <hip/hip_runtime.h>
#include <math.h>

#define N_NODES 50000
#define N_EDGES 640000
// ws layout (float offsets)
#define F_WV   0u
#define F_Z    6400000u
#define F_ST   6800000u           // 4 x 512 floats: A,B,C,D
#define F_QH   6802048u
#define F_KH   13202048u
#define F_VH   19602048u
#define F_HH   26002048u
#define F_PEB  32402048u          // bf16 region: E*128 ushorts (pe, then score)
#define ZERO_FLOATS 6802048u      // wV + z + stats

typedef __attribute__((ext_vector_type(8))) short short8;
typedef __attribute__((ext_vector_type(4))) float f32x4;

__device__ __forceinline__ unsigned short f2bf_(float f) {
    union { float f; unsigned u; } v; v.f = f;
    unsigned r = v.u + 0x7FFFu + ((v.u >> 16) & 1u);
    return (unsigned short)(r >> 16);
}
__device__ __forceinline__ float bf2f_(unsigned short s) {
    union { unsigned u; float f; } v; v.u = ((unsigned)s) << 16;
    return v.f;
}

// ---------------------------------------------------------------------------
// fp32 [rows,128]@[128,128] GEMM (h-side), 64-row tiles, 256 threads.
// ---------------------------------------------------------------------------
template<bool IN_ATTN, bool BIASRES, bool STATS>
__global__ __launch_bounds__(256) void gemm128(
    const float* __restrict__ X, const float* __restrict__ Wt,
    const float* __restrict__ bias, const float* __restrict__ res,
    const float* __restrict__ zden, float* __restrict__ Y,
    float* __restrict__ stats, int rows)
{
    __shared__ float Ws[32][128];
    __shared__ float Xs[32][68];

    const int tid = threadIdx.x;
    const int tx = tid & 31;
    const int ty = tid >> 5;
    const int rbase = blockIdx.x * 64;

    float acc[8][4];
#pragma unroll
    for (int i = 0; i < 8; i++)
#pragma unroll
        for (int j = 0; j < 4; j++) acc[i][j] = 0.f;

    for (int k0 = 0; k0 < 128; k0 += 32) {
#pragma unroll
        for (int j = 0; j < 4; j++) {
            int idx = tid + 256 * j;
            int kk = idx >> 5, c4 = idx & 31;
            *(float4*)&Ws[kk][c4 * 4] = *(const float4*)&Wt[(k0 + kk) * 128 + c4 * 4];
        }
#pragma unroll
        for (int j = 0; j < 8; j++) {
            int idx = tid + 256 * j;
            int row = idx >> 5, kk = idx & 31;
            int gr = rbase + row;
            float v = 0.f;
            if (gr < rows) {
                v = X[gr * 128 + k0 + kk];
                if (IN_ATTN) v = v / (zden[gr * 8 + ((k0 + kk) >> 4)] + 1e-6f);
            }
            Xs[kk][row] = v;
        }
        __syncthreads();
#pragma unroll
        for (int kk = 0; kk < 32; kk++) {
            float4 w4 = *(float4*)&Ws[kk][tx * 4];
            float4 xa = *(float4*)&Xs[kk][ty * 8];
            float4 xb = *(float4*)&Xs[kk][ty * 8 + 4];
            float xr[8] = {xa.x, xa.y, xa.z, xa.w, xb.x, xb.y, xb.z, xb.w};
#pragma unroll
            for (int i = 0; i < 8; i++) {
                acc[i][0] += xr[i] * w4.x;
                acc[i][1] += xr[i] * w4.y;
                acc[i][2] += xr[i] * w4.z;
                acc[i][3] += xr[i] * w4.w;
            }
        }
        __syncthreads();
    }

    const int c0 = tx * 4;
    float colsum[4] = {0, 0, 0, 0}, colsq[4] = {0, 0, 0, 0};
#pragma unroll
    for (int i = 0; i < 8; i++) {
        int gr = rbase + ty * 8 + i;
        if (gr < rows) {
            float4 y;
            float* yv = (float*)&y;
#pragma unroll
            for (int j = 0; j < 4; j++) {
                float v = acc[i][j];
                if (BIASRES) v += bias[c0 + j] + res[gr * 128 + c0 + j];
                yv[j] = v;
                if (STATS) { colsum[j] += v; colsq[j] += v * v; }
            }
            *(float4*)&Y[gr * 128 + c0] = y;
        }
    }
    if (STATS) {
        __syncthreads();
        float* red = &Ws[0][0];
#pragma unroll
        for (int j = 0; j < 4; j++) {
            red[ty * 128 + c0 + j] = colsum[j];
            red[1024 + ty * 128 + c0 + j] = colsq[j];
        }
        __syncthreads();
        if (tid < 128) {
            float s = 0.f, q = 0.f;
#pragma unroll
            for (int t = 0; t < 8; t++) {
                s += red[t * 128 + tid];
                q += red[1024 + t * 128 + tid];
            }
            atomicAdd(&stats[tid], s);
            atomicAdd(&stats[128 + tid], q);
        }
    }
}

// ---------------------------------------------------------------------------
// bf16 MFMA GEMM: [M,128]@[128,128], M multiple of 64. 256 thr, 4 waves 2Mx2N.
// ABF16: A already bf16. OUT 0: bf16 store. OUT 1: +bias+res(fp32)+stats, f32.
// Frag layout (verified m89/m91/m92): A row=lane&15,k=(lane>>4)*8+i;
// B col=lane&15 (W^T rows), same k; D col=lane&15,row=(lane>>4)*4+reg.
// ---------------------------------------------------------------------------
template<bool ABF16, int OUT>
__global__ __launch_bounds__(256) void mgemm_e128(
    const void* __restrict__ Aptr, const float* __restrict__ W,
    const float* __restrict__ bias, const float* __restrict__ res,
    void* __restrict__ Yptr, float* __restrict__ stats)
{
    __shared__ unsigned short Ash[64][136];   // 17.4 KB  (pad: 2-way banks)
    __shared__ unsigned short Wsh[128][40];   // 10.0 KB  W^T chunk [col][k]

    const int tid = threadIdx.x;
    const int lane = tid & 63, wid = tid >> 6;
    const int wm = wid >> 1, wn = wid & 1;
    const long rbase = (long)blockIdx.x * 64;

    // stage A (all K=128) -> bf16 LDS
    if (ABF16) {
        const unsigned short* A = (const unsigned short*)Aptr;
#pragma unroll
        for (int j = 0; j < 4; j++) {
            int idx = tid + 256 * j;          // 1024 short8 groups
            int row = idx >> 4, k8 = (idx & 15) * 8;
            *(short8*)&Ash[row][k8] = *(const short8*)&A[(rbase + row) * 128 + k8];
        }
    } else {
        const float* A = (const float*)Aptr;
#pragma unroll
        for (int j = 0; j < 8; j++) {
            int idx = tid + 256 * j;          // 2048 float4 groups
            int row = idx >> 5, c4 = (idx & 31) * 4;
            float4 v = *(const float4*)&A[(rbase + row) * 128 + c4];
            unsigned short t[4] = {f2bf_(v.x), f2bf_(v.y), f2bf_(v.z), f2bf_(v.w)};
            *(uint2*)&Ash[row][c4] = *(uint2*)t;
        }
    }

    f32x4 acc[2][4];
#pragma unroll
    for (int mi = 0; mi < 2; mi++)
#pragma unroll
        for (int ni = 0; ni < 4; ni++) acc[mi][ni] = (f32x4){0.f, 0.f, 0.f, 0.f};

    const int klo = (lane >> 4) * 8;
    for (int ks = 0; ks < 4; ks++) {
        // stage W chunk [32k][128c] -> Wsh[c][k] (transpose + bf16)
#pragma unroll
        for (int j = 0; j < 4; j++) {
            int idx = tid + 256 * j;          // 1024 float4
            int kk = idx >> 5, c4 = (idx & 31) * 4;
            float4 v = *(const float4*)&W[(ks * 32 + kk) * 128 + c4];
            Wsh[c4 + 0][kk] = f2bf_(v.x);
            Wsh[c4 + 1][kk] = f2bf_(v.y);
            Wsh[c4 + 2][kk] = f2bf_(v.z);
            Wsh[c4 + 3][kk] = f2bf_(v.w);
        }
        __syncthreads();
        short8 af[2], bf[4];
#pragma unroll
        for (int mi = 0; mi < 2; mi++)
            af[mi] = *(const short8*)&Ash[wm * 32 + mi * 16 + (lane & 15)][ks * 32 + klo];
#pragma unroll
        for (int ni = 0; ni < 4; ni++)
            bf[ni] = *(const short8*)&Wsh[wn * 64 + ni * 16 + (lane & 15)][klo];
#pragma unroll
        for (int mi = 0; mi < 2; mi++)
#pragma unroll
            for (int ni = 0; ni < 4; ni++)
                acc[mi][ni] = __builtin_amdgcn_mfma_f32_16x16x32_bf16(af[mi], bf[ni], acc[mi][ni], 0, 0, 0);
        __syncthreads();
    }

    if (OUT == 0) {
        unsigned short* Yb = (unsigned short*)Yptr;
#pragma unroll
        for (int mi = 0; mi < 2; mi++)
#pragma unroll
            for (int ni = 0; ni < 4; ni++) {
                int gc = wn * 64 + ni * 16 + (lane & 15);
#pragma unroll
                for (int r = 0; r < 4; r++) {
                    long gr = rbase + wm * 32 + mi * 16 + (lane >> 4) * 4 + r;
                    Yb[gr * 128 + gc] = f2bf_(acc[mi][ni][r]);
                }
            }
    } else {
        float* Yf = (float*)Yptr;
        float cs[4] = {0, 0, 0, 0}, cq[4] = {0, 0, 0, 0};
#pragma unroll
        for (int mi = 0; mi < 2; mi++)
#pragma unroll
            for (int ni = 0; ni < 4; ni++) {
                int gc = wn * 64 + ni * 16 + (lane & 15);
                float bb = bias[gc];
#pragma unroll
                for (int r = 0; r < 4; r++) {
                    long gr = rbase + wm * 32 + mi * 16 + (lane >> 4) * 4 + r;
                    float v = acc[mi][ni][r] + bb + res[gr * 128 + gc];
                    Yf[gr * 128 + gc] = v;
                    cs[ni] += v; cq[ni] += v * v;
                }
            }
#pragma unroll
        for (int ni = 0; ni < 4; ni++) {
            float s = cs[ni], q = cq[ni];
            s += __shfl_xor(s, 16); s += __shfl_xor(s, 32);
            q += __shfl_xor(q, 16); q += __shfl_xor(q, 32);
            if (lane < 16) {
                int gc = wn * 64 + ni * 16 + lane;
                atomicAdd(&stats[gc], s);
                atomicAdd(&stats[128 + gc], q);
            }
        }
    }
}

// ---------------------------------------------------------------------------
// Edge attention: pe bf16 in, score bf16 out (may alias), wV/z fp32 atomics.
// ---------------------------------------------------------------------------
__global__ __launch_bounds__(256) void edge_attn(
    const int* __restrict__ src, const int* __restrict__ dst,
    const float* __restrict__ Qh, const float* __restrict__ Kh,
    const float* __restrict__ Vh, const unsigned short* __restrict__ pe,
    unsigned short* __restrict__ score, float* __restrict__ wV, float* __restrict__ z)
{
    const int wave = threadIdx.x >> 6, lane = threadIdx.x & 63;
    const int eid = blockIdx.x * 4 + wave;
    const int s = src[eid], d = dst[eid];
    const int f = lane * 2;
    float2 k2 = *(const float2*)&Kh[s * 128 + f];
    float2 q2 = *(const float2*)&Qh[d * 128 + f];
    ushort2 p2 = *(const ushort2*)&pe[(size_t)eid * 128 + f];
    float scx = k2.x * q2.x * 0.25f * bf2f_(p2.x);
    float scy = k2.y * q2.y * 0.25f * bf2f_(p2.y);
    ushort2 so; so.x = f2bf_(scx); so.y = f2bf_(scy);
    *(ushort2*)&score[(size_t)eid * 128 + f] = so;
    float sh = scx + scy;
    sh += __shfl_xor(sh, 1);
    sh += __shfl_xor(sh, 2);
    sh += __shfl_xor(sh, 4);
    float w = __expf(fminf(fmaxf(sh, -5.f), 5.f));
    float2 v2 = *(const float2*)&Vh[s * 128 + f];
    atomicAdd(&wV[d * 128 + f], v2.x * w);
    atomicAdd(&wV[d * 128 + f + 1], v2.y * w);
    if ((lane & 7) == 0) atomicAdd(&z[d * 8 + (lane >> 3)], w);
}

// ---------------------------------------------------------------------------
// fp32 fused BN1+FFN for h-side (unchanged skeleton).
// ---------------------------------------------------------------------------
__global__ __launch_bounds__(256) void ffn_bn(
    const float* __restrict__ Xpre, const float* __restrict__ st1,
    const float* __restrict__ g1, const float* __restrict__ b1,
    const float* __restrict__ W1, const float* __restrict__ bf1,
    const float* __restrict__ W2, const float* __restrict__ bf2,
    float* __restrict__ Y, float* __restrict__ stats2, int rows)
{
    __shared__ float Xn[128][36];
    __shared__ float tbuf[32][256];
    __shared__ float Wc[4096];

    const int tid = threadIdx.x;
    const int rbase = blockIdx.x * 32;

#pragma unroll
    for (int j = 0; j < 16; j++) {
        int idx = tid + 256 * j;
        int row = idx >> 7, c = idx & 127;
        int gr = rbase + row;
        float v = 0.f;
        if (gr < rows)
            v = (Xpre[(size_t)gr * 128 + c] - st1[256 + c]) * st1[384 + c] * g1[c] + b1[c];
        Xn[c][row] = v;
    }

    const int txx = tid & 63;
    const int tyy = tid >> 6;
    float acc1[8][4];
#pragma unroll
    for (int i = 0; i < 8; i++)
#pragma unroll
        for (int j = 0; j < 4; j++) acc1[i][j] = 0.f;

    for (int k0 = 0; k0 < 128; k0 += 16) {
        __syncthreads();
#pragma unroll
        for (int j = 0; j < 4; j++) {
            int idx = tid + 256 * j;
            int kk = idx >> 6, c4 = idx & 63;
            *(float4*)&Wc[kk * 256 + c4 * 4] = *(const float4*)&W1[(k0 + kk) * 256 + c4 * 4];
        }
        __syncthreads();
#pragma unroll
        for (int kk = 0; kk < 16; kk++) {
            float4 w4 = *(float4*)&Wc[kk * 256 + txx * 4];
            float4 xa = *(float4*)&Xn[k0 + kk][tyy * 8];
            float4 xb = *(float4*)&Xn[k0 + kk][tyy * 8 + 4];
            float xr[8] = {xa.x, xa.y, xa.z, xa.w, xb.x, xb.y, xb.z, xb.w};
#pragma unroll
            for (int i = 0; i < 8; i++) {
                acc1[i][0] += xr[i] * w4.x;
                acc1[i][1] += xr[i] * w4.y;
                acc1[i][2] += xr[i] * w4.z;
                acc1[i][3] += xr[i] * w4.w;
            }
        }
    }
    {
        float4 b1v = *(const float4*)&bf1[txx * 4];
#pragma unroll
        for (int i = 0; i < 8; i++) {
            int r = tyy * 8 + i;
            float4 tv;
            tv.x = fmaxf(acc1[i][0] + b1v.x, 0.f);
            tv.y = fmaxf(acc1[i][1] + b1v.y, 0.f);
            tv.z = fmaxf(acc1[i][2] + b1v.z, 0.f);
            tv.w = fmaxf(acc1[i][3] + b1v.w, 0.f);
            *(float4*)&tbuf[r][txx * 4] = tv;
        }
    }

    const int tx2 = tid & 31;
    const int ty2 = tid >> 5;
    float acc2[4][4];
#pragma unroll
    for (int i = 0; i < 4; i++)
#pragma unroll
        for (int j = 0; j < 4; j++) acc2[i][j] = 0.f;

    for (int k0 = 0; k0 < 256; k0 += 32) {
        __syncthreads();
#pragma unroll
        for (int j = 0; j < 4; j++) {
            int idx = tid + 256 * j;
            int kk = idx >> 5, c4 = idx & 31;
            *(float4*)&Wc[kk * 128 + c4 * 4] = *(const float4*)&W2[(k0 + kk) * 128 + c4 * 4];
        }
        __syncthreads();
#pragma unroll
        for (int kk = 0; kk < 32; kk++) {
            float4 w4 = *(float4*)&Wc[kk * 128 + tx2 * 4];
            float tr[4];
#pragma unroll
            for (int i = 0; i < 4; i++) tr[i] = tbuf[ty2 * 4 + i][k0 + kk];
#pragma unroll
            for (int i = 0; i < 4; i++) {
                acc2[i][0] += tr[i] * w4.x;
                acc2[i][1] += tr[i] * w4.y;
                acc2[i][2] += tr[i] * w4.z;
                acc2[i][3] += tr[i] * w4.w;
            }
        }
    }

    const int c0 = tx2 * 4;
    float colsum[4] = {0, 0, 0, 0}, colsq[4] = {0, 0, 0, 0};
    float4 b2v = *(const float4*)&bf2[c0];
#pragma unroll
    for (int i = 0; i < 4; i++) {
        int r = ty2 * 4 + i;
        int gr = rbase + r;
        if (gr < rows) {
            float4 y;
            float* yv = (float*)&y;
            float bb[4] = {b2v.x, b2v.y, b2v.z, b2v.w};
#pragma unroll
            for (int j = 0; j < 4; j++) {
                float v = acc2[i][j] + bb[j] + Xn[c0 + j][r];
                yv[j] = v;
                colsum[j] += v;
                colsq[j] += v * v;
            }
            *(float4*)&Y[(size_t)gr * 128 + c0] = y;
        }
    }
    __syncthreads();
#pragma unroll
    for (int j = 0; j < 4; j++) {
        Wc[ty2 * 128 + c0 + j] = colsum[j];
        Wc[1024 + ty2 * 128 + c0 + j] = colsq[j];
    }
    __syncthreads();
    if (tid < 128) {
        float s = 0.f, q = 0.f;
#pragma unroll
        for (int t = 0; t < 8; t++) {
            s += Wc[t * 128 + tid];
            q += Wc[1024 + t * 128 + tid];
        }
        atomicAdd(&stats2[tid], s);
        atomicAdd(&stats2[128 + tid], q);
    }
}

// ---------------------------------------------------------------------------
// Fused MFMA FFN for e-side: y = relu(BN1(x)@W1+b1)@W2+b2+BN1(x), BN2 stats.
// 64-row tiles, 256 thr, 4 waves (2Mx2N). t kept in LDS bf16. In-place safe.
// LDS: Xn 17.4K + Tb 33.8K + Wst 20.5K = 71.7KB -> 2 blocks/CU.
// ---------------------------------------------------------------------------
__global__ __launch_bounds__(256) void ffn_e_mfma(
    const float* __restrict__ Xpre, const float* __restrict__ st1,
    const float* __restrict__ g1, const float* __restrict__ b1,
    const float* __restrict__ W1, const float* __restrict__ bf1,
    const float* __restrict__ W2, const float* __restrict__ bf2,
    float* __restrict__ Y, float* __restrict__ stats2)
{
    __shared__ unsigned short Xn[64][136];
    __shared__ unsigned short Tb[64][264];
    __shared__ unsigned short Wst[256][40];

    const int tid = threadIdx.x;
    const int lane = tid & 63, wid = tid >> 6;
    const int wm = wid >> 1, wn = wid & 1;
    const long rbase = (long)blockIdx.x * 64;
    const int klo = (lane >> 4) * 8;

    // stage Xn = bf16(BN1(Xpre))
#pragma unroll
    for (int j = 0; j < 8; j++) {
        int idx = tid + 256 * j;
        int row = idx >> 5, c4 = (idx & 31) * 4;
        float4 v = *(const float4*)&Xpre[(rbase + row) * 128 + c4];
        unsigned short t[4];
        float* vv = (float*)&v;
#pragma unroll
        for (int m = 0; m < 4; m++) {
            int c = c4 + m;
            t[m] = f2bf_((vv[m] - st1[256 + c]) * st1[384 + c] * g1[c] + b1[c]);
        }
        *(uint2*)&Xn[row][c4] = *(uint2*)t;
    }

    // GEMM1: [64,128]@[128,256] -> relu -> Tb (bf16)
    f32x4 acc1[2][8];
#pragma unroll
    for (int mi = 0; mi < 2; mi++)
#pragma unroll
        for (int ni = 0; ni < 8; ni++) acc1[mi][ni] = (f32x4){0.f, 0.f, 0.f, 0.f};

    for (int ks = 0; ks < 4; ks++) {
#pragma unroll
        for (int j = 0; j < 8; j++) {
            int idx = tid + 256 * j;          // 2048 float4 over [32][256]
            int kk = idx >> 6, c4 = (idx & 63) * 4;
            float4 v = *(const float4*)&W1[(ks * 32 + kk) * 256 + c4];
            Wst[c4 + 0][kk] = f2bf_(v.x);
            Wst[c4 + 1][kk] = f2bf_(v.y);
            Wst[c4 + 2][kk] = f2bf_(v.z);
            Wst[c4 + 3][kk] = f2bf_(v.w);
        }
        __syncthreads();
        short8 af[2], bfr[8];
#pragma unroll
        for (int mi = 0; mi < 2; mi++)
            af[mi] = *(const short8*)&Xn[wm * 32 + mi * 16 + (lane & 15)][ks * 32 + klo];
#pragma unroll
        for (int ni = 0; ni < 8; ni++)
            bfr[ni] = *(const short8*)&Wst[wn * 128 + ni * 16 + (lane & 15)][klo];
#pragma unroll
        for (int mi = 0; mi < 2; mi++)
#pragma unroll
            for (int ni = 0; ni < 8; ni++)
                acc1[mi][ni] = __builtin_amdgcn_mfma_f32_16x16x32_bf16(af[mi], bfr[ni], acc1[mi][ni], 0, 0, 0);
        __syncthreads();
    }
    // t = relu(acc1 + bf1) -> Tb
#pragma unroll
    for (int mi = 0; mi < 2; mi++)
#pragma unroll
        for (int ni = 0; ni < 8; ni++) {
            int gc = wn * 128 + ni * 16 + (lane & 15);
            float bb = bf1[gc];
#pragma unroll
            for (int r = 0; r < 4; r++) {
                int row = wm * 32 + mi * 16 + (lane >> 4) * 4 + r;
                Tb[row][gc] = f2bf_(fmaxf(acc1[mi][ni][r] + bb, 0.f));
            }
        }

    // GEMM2: [64,256]@[256,128]
    f32x4 acc2[2][4];
#pragma unroll
    for (int mi = 0; mi < 2; mi++)
#pragma unroll
        for (int ni = 0; ni < 4; ni++) acc2[mi][ni] = (f32x4){0.f, 0.f, 0.f, 0.f};

    for (int ks = 0; ks < 8; ks++) {
#pragma unroll
        for (int j = 0; j < 4; j++) {
            int idx = tid + 256 * j;          // 1024 float4 over [32][128]
            int kk = idx >> 5, c4 = (idx & 31) * 4;
            float4 v = *(const float4*)&W2[(ks * 32 + kk) * 128 + c4];
            Wst[c4 + 0][kk] = f2bf_(v.x);
            Wst[c4 + 1][kk] = f2bf_(v.y);
            Wst[c4 + 2][kk] = f2bf_(v.z);
            Wst[c4 + 3][kk] = f2bf_(v.w);
        }
        __syncthreads();
        short8 af[2], bfr[4];
#pragma unroll
        for (int mi = 0; mi < 2; mi++)
            af[mi] = *(const short8*)&Tb[wm * 32 + mi * 16 + (lane & 15)][ks * 32 + klo];
#pragma unroll
        for (int ni = 0; ni < 4; ni++)
            bfr[ni] = *(const short8*)&Wst[wn * 64 + ni * 16 + (lane & 15)][klo];
#pragma unroll
        for (int mi = 0; mi < 2; mi++)
#pragma unroll
            for (int ni = 0; ni < 4; ni++)
                acc2[mi][ni] = __builtin_amdgcn_mfma_f32_16x16x32_bf16(af[mi], bfr[ni], acc2[mi][ni], 0, 0, 0);
        __syncthreads();
    }

    // epilogue: y = acc2 + bf2 + BN1(x)(bf16-rounded), stats2
    float cs[4] = {0, 0, 0, 0}, cq[4] = {0, 0, 0, 0};
#pragma unroll
    for (int mi = 0; mi < 2; mi++)
#pragma unroll
        for (int ni = 0; ni < 4; ni++) {
            int gc = wn * 64 + ni * 16 + (lane & 15);
            float bb = bf2[gc];
#pragma unroll
            for (int r = 0; r < 4; r++) {
                int row = wm * 32 + mi * 16 + (lane >> 4) * 4 + r;
                long gr = rbase + row;
                float v = acc2[mi][ni][r] + bb + bf2f_(Xn[row][gc]);
                Y[gr * 128 + gc] = v;
                cs[ni] += v; cq[ni] += v * v;
            }
        }
#pragma unroll
    for (int ni = 0; ni < 4; ni++) {
        float s = cs[ni], q = cq[ni];
        s += __shfl_xor(s, 16); s += __shfl_xor(s, 32);
        q += __shfl_xor(q, 16); q += __shfl_xor(q, 32);
        if (lane < 16) {
            int gc = wn * 64 + ni * 16 + lane;
            atomicAdd(&stats2[gc], s);
            atomicAdd(&stats2[128 + gc], q);
        }
    }
}

// stats buffer: [0:128)=sum, [128:256)=sumsq, [256:384)=mean, [384:512)=rstd
__global__ void finalize_stats(float* st, float n)
{
    int c = threadIdx.x;
    float m = st[c] / n;
    float v = st[128 + c] / n - m * m;
    st[256 + c] = m;
    st[384 + c] = rsqrtf(v + 1e-5f);
}

__global__ __launch_bounds__(256) void bn_apply(
    const float4* __restrict__ X, const float* __restrict__ st,
    const float* __restrict__ g, const float* __restrict__ b,
    float4* __restrict__ Y, int n4)
{
    int i = blockIdx.x * 256 + threadIdx.x;
    if (i >= n4) return;
    int c0 = (i & 31) * 4;
    float4 x = X[i];
    float4 y;
    y.x = (x.x - st[256 + c0 + 0]) * st[384 + c0 + 0] * g[c0 + 0] + b[c0 + 0];
    y.y = (x.y - st[256 + c0 + 1]) * st[384 + c0 + 1] * g[c0 + 1] + b[c0 + 1];
    y.z = (x.z - st[256 + c0 + 2]) * st[384 + c0 + 2] * g[c0 + 2] + b[c0 + 2];
    y.w = (x.w - st[256 + c0 + 3]) * st[384 + c0 + 3] * g[c0 + 3] + b[c0 + 3];
    Y[i] = y;
}

extern "C" void kernel_launch(void* const* d_in, const int* in_sizes, int n_in,
                              void* d_out, int out_size, void* d_ws, size_t ws_size,
                              hipStream_t stream)
{
    const float* h    = (const float*)d_in[0];
    const float* e    = (const float*)d_in[1];
    const int*   src  = (const int*)d_in[2];
    const int*   dst  = (const int*)d_in[3];
    const float* Wq   = (const float*)d_in[4];
    const float* Wk   = (const float*)d_in[5];
    const float* Wv   = (const float*)d_in[6];
    const float* We   = (const float*)d_in[7];
    const float* Wo_h = (const float*)d_in[8];
    const float* bo_h = (const float*)d_in[9];
    const float* Wo_e = (const float*)d_in[10];
    const float* bo_e = (const float*)d_in[11];
    const float* g1h  = (const float*)d_in[12];
    const float* b1h  = (const float*)d_in[13];
    const float* g1e  = (const float*)d_in[14];
    const float* b1e  = (const float*)d_in[15];
    const float* Wf1h = (const float*)d_in[16];
    const float* bf1h = (const float*)d_in[17];
    const float* Wf2h = (const float*)d_in[18];
    const float* bf2h = (const float*)d_in[19];
    const float* Wf1e = (const float*)d_in[20];
    const float* bf1e = (const float*)d_in[21];
    const float* Wf2e = (const float*)d_in[22];
    const float* bf2e = (const float*)d_in[23];
    const float* g2h  = (const float*)d_in[24];
    const float* b2h  = (const float*)d_in[25];
    const float* g2e  = (const float*)d_in[26];
    const float* b2e  = (const float*)d_in[27];

    float* out = (float*)d_out;
    float* ws  = (float*)d_ws;

    float* wV     = ws + F_WV;
    float* z      = ws + F_Z;
    float* statsA = ws + F_ST;
    float* statsB = ws + F_ST + 512;
    float* statsC = ws + F_ST + 1024;
    float* statsD = ws + F_ST + 1536;
    float* Qh     = ws + F_QH;
    float* Kh     = ws + F_KH;
    float* Vh     = ws + F_VH;
    float* hh_pre = ws + F_HH;
    unsigned short* peb = (unsigned short*)(ws + F_PEB);   // pe, then score (alias)

    float* out_h  = out;                                   // h2 pre-BN2, then final
    float* out_e  = out + (size_t)N_NODES * 128;           // ee_pre, e2, final

    hipMemsetAsync(ws, 0, (size_t)ZERO_FLOATS * sizeof(float), stream);

    dim3 blk(256);
    const int gN = (N_NODES + 63) / 64;     // 782
    const int gE = N_EDGES / 64;            // 10000
    const int fN = (N_NODES + 31) / 32;     // 1563

    // h projections (fp32)
    gemm128<false, false, false><<<gN, blk, 0, stream>>>(h, Wq, nullptr, nullptr, nullptr, Qh, nullptr, N_NODES);
    gemm128<false, false, false><<<gN, blk, 0, stream>>>(h, Wk, nullptr, nullptr, nullptr, Kh, nullptr, N_NODES);
    gemm128<false, false, false><<<gN, blk, 0, stream>>>(h, Wv, nullptr, nullptr, nullptr, Vh, nullptr, N_NODES);
    // e projection (MFMA, bf16 out)
    mgemm_e128<false, 0><<<gE, blk, 0, stream>>>(e, We, nullptr, nullptr, peb, nullptr);

    // edge attention + scatter (score aliases pe)
    edge_attn<<<N_EDGES / 4, blk, 0, stream>>>(src, dst, Qh, Kh, Vh, peb, peb, wV, z);

    // attn-out projections + residual + BN1 stats
    gemm128<true, true, true><<<gN, blk, 0, stream>>>(wV, Wo_h, bo_h, h, z, hh_pre, statsA, N_NODES);
    mgemm_e128<true, 1><<<gE, blk, 0, stream>>>(peb, Wo_e, bo_e, e, out_e, statsB);

    finalize_stats<<<1, 128, 0, stream>>>(statsA, (float)N_NODES);
    finalize_stats<<<1, 128, 0, stream>>>(statsB, (float)N_EDGES);

    // FFN + BN2 stats
    ffn_bn<<<fN, blk, 0, stream>>>(hh_pre, statsA, g1h, b1h, Wf1h, bf1h, Wf2h, bf2h, out_h, statsC, N_NODES);
    ffn_e_mfma<<<gE, blk, 0, stream>>>(out_e, statsB, g1e, b1e, Wf1e, bf1e, Wf2e, bf2e, out_e, statsD);

    finalize_stats<<<1, 128, 0, stream>>>(statsC, (float)N_NODES);
    finalize_stats<<<1, 128, 0, stream>>>(statsD, (float)N_EDGES);

    // final BN apply (in place)
    bn_apply<<<(N_NODES * 128 / 4 + 255) / 256, blk, 0, stream>>>(
        (const float4*)out_h, statsC, g2h, b2h, (float4*)out_h, N_NODES * 128 / 4);
    bn_apply<<<((int)((size_t)N_EDGES * 128 / 4) + 255) / 256, blk, 0, stream>>>(
        (const float4*)out_e, statsD, g2e, b2e, (float4*)out_e, (int)((size_t)N_EDGES * 128 / 4));
}